// Round 20
// baseline (176.330 us; speedup 1.0000x reference)
//
#include <hip/hip_runtime.h>
#include <hip/hip_bf16.h>

#define BATCH 16
#define CINC 96
#define HGT 112
#define WID 112
#define HW 12544          // 112*112
#define C1N 192
#define C2N 384
#define EPSV 1e-5f

typedef _Float16 f16x8 __attribute__((ext_vector_type(8)));
typedef _Float16 f16x4 __attribute__((ext_vector_type(4)));
typedef float    f32x4 __attribute__((ext_vector_type(4)));

// d_ws layout (float offsets unless noted)
#define WS_S      0        // 16*96 f32 h-sums (zeroed each launch)
#define WS_A1B1   1536     // 16*192 f32
#define WS_W1F    4608     // 192*3
#define WS_B1F    5184     // 192
#define WS_W2F    5376     // 384*3
#define WS_B2F    6528     // 384
#define WS_S3     6912     // 96
#define WS_B3     7008     // 96
#define WS_WPF_BYTES (7104*4)                    // f16 wpf[chunk][ks][rt][lane][8]
#define WS_H_BYTES   (WS_WPF_BYTES + CINC*C2N*2) // f16 h[16][96][12544] = 38.5 MB

// ---------------- prep: fold BN into weights; Wp -> chunk-contiguous fragments --
__global__ void k_prep(const float* __restrict__ wdw1, const float* __restrict__ g1,
                       const float* __restrict__ bb1, const float* __restrict__ m1,
                       const float* __restrict__ v1,
                       const float* __restrict__ wdw2, const float* __restrict__ g2,
                       const float* __restrict__ bb2, const float* __restrict__ m2,
                       const float* __restrict__ v2,
                       const float* __restrict__ wpw, const float* __restrict__ g3,
                       const float* __restrict__ bb3, const float* __restrict__ m3,
                       const float* __restrict__ v3,
                       float* ws)
{
    int t = blockIdx.x * blockDim.x + threadIdx.x;
    int stride = gridDim.x * blockDim.x;
    float* w1f = ws + WS_W1F; float* b1f = ws + WS_B1F;
    float* w2f = ws + WS_W2F; float* b2f = ws + WS_B2F;
    float* s3  = ws + WS_S3;  float* b3f = ws + WS_B3;
    _Float16* wpf = (_Float16*)((char*)ws + WS_WPF_BYTES);

    for (int c = t; c < C1N; c += stride) {
        float s = g1[c] / sqrtf(v1[c] + EPSV);
        w1f[c*3+0] = wdw1[c*3+0] * s;
        w1f[c*3+1] = wdw1[c*3+1] * s;
        w1f[c*3+2] = wdw1[c*3+2] * s;
        b1f[c] = bb1[c] - m1[c] * s;
    }
    for (int c = t; c < C2N; c += stride) {
        float s = g2[c] / sqrtf(v2[c] + EPSV);
        w2f[c*3+0] = wdw2[c*3+0] * s;
        w2f[c*3+1] = wdw2[c*3+1] * s;
        w2f[c*3+2] = wdw2[c*3+2] * s;
        b2f[c] = bb2[c] - m2[c] * s;
    }
    for (int c = t; c < CINC; c += stride) {
        float s = g3[c] / sqrtf(v3[c] + EPSV);
        s3[c] = s; b3f[c] = bb3[c] - m3[c] * s;
    }
    for (int idx = t; idx < CINC * C2N; idx += stride) {
        int e = idx & 7;
        int l2 = idx >> 3;
        int lane = l2 & 63;
        int l3 = l2 >> 6;
        int rt = l3 % 6, ksg = l3 / 6;
        int m = rt * 16 + (lane & 15);
        int k = ksg * 32 + (lane >> 4) * 8 + e;
        int o = (k & 63) * 6 + (k >> 6);
        wpf[idx] = (_Float16)wpw[m * C2N + o];
    }
}

// x-data for one channel pair: 3 row vectors + left/right boundary scalars
struct PairX {
    f32x4 T[2], M[2], B[2];
    float Ls[2][3], Rs[2][3];   // [q][row: 0=T,1=M,2=B], clamped loads
};

// ---------------- main: shfl-free dw gather -> LDS Wp MFMA -> h+sums -----------
// block = 4 rows x 64 cols; 72 KB LDS -> 2 blk/CU
__global__ __launch_bounds__(256, 2) void k_main12(const float* __restrict__ x,
                                                   const float* __restrict__ ws,
                                                   float* __restrict__ sums,
                                                   _Float16* __restrict__ h_out)
{
    __shared__ __align__(16) char u_raw[256 * 208];   // u tile (slot-rotated); h_s aliases
    __shared__ __align__(16) f16x8 wpf_s[1152];       // Wp chunk fragments (18432 B)
    __shared__ float ssum[CINC];

    int t   = threadIdx.x;
    int bid = blockIdx.x;
    int logical = (bid & 7) * 112 + (bid >> 3);       // XCD-chunked (896 = 8*112)
    int b   = logical / 56;
    int rem = logical - b * 56;
    int y0  = (rem >> 1) * 4;
    int x0  = (rem & 1) * 48;

    int wv = t >> 6, lane = t & 63;
    int r = lane >> 4, c4 = lane & 15;
    int gy = y0 + r;
    int gc = x0 + 4 * c4;
    int col16 = c4, g = r;                            // MFMA-phase aliases

    const float* w1f = ws + WS_W1F; const float* b1f = ws + WS_B1F;
    const float* w2f = ws + WS_W2F; const float* b2f = ws + WS_B2F;

    if (t < CINC) ssum[t] = 0.f;

    bool ymok = gy >= 1;
    bool ypok = gy + 1 < HGT;
    bool lok  = (gc > 0);                  // left neighbor col in image
    bool rok  = (gc + 4 < WID);            // right neighbor col in image
    int  lco  = lok ? gc - 1 : gc;         // clamped addresses
    int  rco  = rok ? gc + 4 : gc;
    int  tm = ymok ? -WID : 0;
    int  tp = ypok ?  WID : 0;

    f32x4 acc[6][4];
    #pragma unroll
    for (int rt = 0; rt < 6; ++rt)
        #pragma unroll
        for (int ct = 0; ct < 4; ++ct) acc[rt][ct] = (f32x4){0.f, 0.f, 0.f, 0.f};

    const f16x8* wpf_g = (const f16x8*)((const char*)ws + WS_WPF_BYTES);
    long xb = (long)b * CINC * HW;
    const float* xw = x + xb + (long)gy * WID;        // + cu*HW + col

    int rotbase = 3 * r + c4;
    char* ub0 = u_raw + (r * 64 + 4 * c4) * 208;

    // prefetch chunk 0's Wp fragments into registers
    f16x8 nw0 = wpf_g[t];
    f16x8 nw1 = wpf_g[256 + t];
    f16x8 nw2 = wpf_g[512 + t];
    f16x8 nw3 = wpf_g[768 + t];
    f16x8 nw4 = nw0;
    if (t < 128) nw4 = wpf_g[1024 + t];

    #define LOADCH(dst, q, cuq) {                                         \
        const float* p_ = xw + (long)(cuq) * HW;                          \
        (dst).M[q] = *(const f32x4*)(p_ + gc);                            \
        (dst).T[q] = *(const f32x4*)(p_ + gc + tm);                       \
        (dst).B[q] = *(const f32x4*)(p_ + gc + tp);                       \
        const float* lq_ = p_ + lco;                                      \
        (dst).Ls[q][0] = lq_[tm]; (dst).Ls[q][1] = lq_[0]; (dst).Ls[q][2] = lq_[tp]; \
        const float* rq_ = p_ + rco;                                      \
        (dst).Rs[q][0] = rq_[tm]; (dst).Rs[q][1] = rq_[0]; (dst).Rs[q][2] = rq_[tp]; }

    for (int chunk = 0; chunk < 4; ++chunk) {
        if (chunk) __syncthreads();       // prev MFMA reads done before overwrite

        // stage Wp fragments from prefetch regs (pure ds_write, no global wait)
        wpf_s[t] = nw0;
        wpf_s[256 + t] = nw1;
        wpf_s[512 + t] = nw2;
        wpf_s[768 + t] = nw3;
        if (t < 128) wpf_s[1024 + t] = nw4;

        int cbase = chunk * 24 + wv * 6;
        PairX A, B;
        LOADCH(A, 0, cbase + 0)
        LOADCH(A, 1, cbase + 1)

        // 3 pairs, software-pipelined: load pair p+1 while computing pair p
        #pragma unroll
        for (int p = 0; p < 3; ++p) {
            if (p == 0) { LOADCH(B, 0, cbase + 2) LOADCH(B, 1, cbase + 3) }
            if (p == 1) { LOADCH(A, 0, cbase + 4) LOADCH(A, 1, cbase + 5) }
            PairX& C = (p == 1) ? B : A;

            f16x4 uv[2][4];
            #pragma unroll
            for (int q = 0; q < 2; ++q) {
                int cu = cbase + 2 * p + q;
                int c1a = cu * 2;
                float wa0 = w1f[c1a*3+0], wa1 = w1f[c1a*3+1], wa2 = w1f[c1a*3+2], ba = b1f[c1a];
                float wb0 = w1f[c1a*3+3], wb1 = w1f[c1a*3+4], wb2 = w1f[c1a*3+5], bb = b1f[c1a+1];

                float va[4], vb[4];
                #pragma unroll
                for (int j = 0; j < 4; ++j) {
                    float tt = ymok ? C.T[q][j] : 0.f;
                    float bt = ypok ? C.B[q][j] : 0.f;
                    va[j] = fmaf(wa0, tt, fmaf(wa1, C.M[q][j], fmaf(wa2, bt, ba)));
                    vb[j] = fmaf(wb0, tt, fmaf(wb1, C.M[q][j], fmaf(wb2, bt, bb)));
                }
                // neighbor columns computed locally (no shfl); conv2 zero-pads
                // the BN1 output, so out-of-image columns contribute 0
                float lT = ymok ? C.Ls[q][0] : 0.f;
                float lB = ypok ? C.Ls[q][2] : 0.f;
                float rT = ymok ? C.Rs[q][0] : 0.f;
                float rB = ypok ? C.Rs[q][2] : 0.f;
                float vLa = lok ? fmaf(wa0, lT, fmaf(wa1, C.Ls[q][1], fmaf(wa2, lB, ba))) : 0.f;
                float vLb = lok ? fmaf(wb0, lT, fmaf(wb1, C.Ls[q][1], fmaf(wb2, lB, bb))) : 0.f;
                float vRa = rok ? fmaf(wa0, rT, fmaf(wa1, C.Rs[q][1], fmaf(wa2, rB, ba))) : 0.f;
                float vRb = rok ? fmaf(wb0, rT, fmaf(wb1, C.Rs[q][1], fmaf(wb2, rB, bb))) : 0.f;

                int c2b = cu * 4;
                float pa[6] = {vLa, va[0], va[1], va[2], va[3], vRa};
                float pb[6] = {vLb, vb[0], vb[1], vb[2], vb[3], vRb};
                #pragma unroll
                for (int j = 0; j < 4; ++j) {
                    #pragma unroll
                    for (int jj = 0; jj < 4; ++jj) {
                        float p0 = (jj < 2) ? pa[j]     : pb[j];
                        float p1 = (jj < 2) ? pa[j + 1] : pb[j + 1];
                        float p2 = (jj < 2) ? pa[j + 2] : pb[j + 2];
                        float tv = fmaf(w2f[(c2b+jj)*3+0], p0,
                                   fmaf(w2f[(c2b+jj)*3+1], p1,
                                   fmaf(w2f[(c2b+jj)*3+2], p2, b2f[c2b+jj])));
                        uv[q][j][jj] = (_Float16)fminf(fmaxf(tv, 0.f), 6.f);
                    }
                }
            }
            // paired 16-B store: k-cell = wv*3+p, rotated
            int slot = (wv * 3 + p + rotbase) % 12;
            char* ubase = ub0 + slot * 16;
            #pragma unroll
            for (int j = 0; j < 4; ++j) {
                f16x8 w = __builtin_shufflevector(uv[0][j], uv[1][j], 0, 1, 2, 3, 4, 5, 6, 7);
                *(f16x8*)(ubase + j * 208) = w;
            }
        }

        // prefetch next chunk's Wp during barrier + MFMA
        if (chunk < 3) {
            int cb = (chunk + 1) * 1152;
            nw0 = wpf_g[cb + t];
            nw1 = wpf_g[cb + 256 + t];
            nw2 = wpf_g[cb + 512 + t];
            nw3 = wpf_g[cb + 768 + t];
            if (t < 128) nw4 = wpf_g[cb + 1024 + t];
        }
        __syncthreads();   // u + wpf_s ready

        // MFMA: acc += Wp[:, chunk slice] * u  (all operands in LDS)
        __builtin_amdgcn_s_setprio(1);
        #pragma unroll
        for (int ks = 0; ks < 3; ++ks) {
            f16x8 bfr[4];
            #pragma unroll
            for (int ct = 0; ct < 4; ++ct) {
                int pos = wv * 64 + ct * 16 + col16;
                int sl = (ks * 4 + g + 3 * wv + ((pos >> 2) & 15)) % 12;
                bfr[ct] = *(const f16x8*)(u_raw + pos * 208 + sl * 16);
            }
            #pragma unroll
            for (int rt = 0; rt < 6; ++rt) {
                f16x8 afr = wpf_s[(ks * 6 + rt) * 64 + lane];
                #pragma unroll
                for (int ct = 0; ct < 4; ++ct)
                    acc[rt][ct] = __builtin_amdgcn_mfma_f32_16x16x32_f16(afr, bfr[ct], acc[rt][ct], 0, 0, 0);
            }
        }
        __builtin_amdgcn_s_setprio(0);
    }
    __syncthreads();   // last MFMA reads done before aliasing u_raw with h

    // stage h (bn3, f16) into LDS: h_s[m][264]
    _Float16* h_s = (_Float16*)u_raw;
    const float* s3  = ws + WS_S3;
    const float* b3f = ws + WS_B3;
    #pragma unroll
    for (int rt = 0; rt < 6; ++rt) {
        #pragma unroll
        for (int ct = 0; ct < 4; ++ct) {
            int p = wv * 64 + ct * 16 + col16;
            #pragma unroll
            for (int rr = 0; rr < 4; ++rr) {
                int m = rt * 16 + g * 4 + rr;
                h_s[m * 264 + p] = (_Float16)fmaf(acc[rt][ct][rr], s3[m], b3f[m]);
            }
        }
    }
    __syncthreads();

    // coalesced full-line h stores + channel sums (overlap cols masked)
    #pragma unroll
    for (int i = 0; i < 12; ++i) {
        int flat = i * 2048 + t * 8;           // covers 96*256 exactly
        int m = flat >> 8;
        int p = flat & 255;
        f16x8 hv = *(const f16x8*)(h_s + m * 264 + p);
        int row = y0 + (p >> 6);
        int colg = x0 + (p & 63);
        *(f16x8*)(h_out + ((long)(b * CINC + m)) * HW + (long)row * WID + colg) = hv;

        float s = 0.f;
        if (!(x0 == 48 && (p & 63) < 16)) {    // overlap cols 48..63 counted by half-0
            #pragma unroll
            for (int e = 0; e < 8; ++e) s += (float)hv[e];
        }
        s += __shfl_xor(s, 1);
        s += __shfl_xor(s, 2);
        s += __shfl_xor(s, 4);
        s += __shfl_xor(s, 8);
        s += __shfl_xor(s, 16);
        if ((lane & 31) == 0) atomicAdd(&ssum[m], s);
    }
    __syncthreads();
    if (t < CINC) atomicAdd(&sums[b * CINC + t], ssum[t]);
}

// ---------------- gates: mean(h) -> fc1+relu -> fc2 -> hardsig -> a1,b1 -------
__global__ __launch_bounds__(192) void k_gates(const float* __restrict__ sums,
                                               const float* __restrict__ fc1w,
                                               const float* __restrict__ fc1b,
                                               const float* __restrict__ fc2w,
                                               const float* __restrict__ fc2b,
                                               float* __restrict__ a1b1)
{
    __shared__ float mean_s[CINC];
    __shared__ float mid[24];
    int b = blockIdx.x;
    int t = threadIdx.x;     // 192

    if (t < CINC) mean_s[t] = sums[b * CINC + t] * (1.0f / 12544.0f);
    __syncthreads();
    if (t < 24) {
        float d = fc1b[t];
        #pragma unroll 4
        for (int c = 0; c < CINC; ++c) d = fmaf(fc1w[t * CINC + c], mean_s[c], d);
        mid[t] = fmaxf(d, 0.f);
    }
    __syncthreads();
    {
        float d = fc2b[t];
        #pragma unroll
        for (int j = 0; j < 24; ++j) d = fmaf(fc2w[t * 24 + j], mid[j], d);
        float y = fminf(fmaxf(d + 3.f, 0.f), 6.f) * (1.f / 6.f);
        y = (y - 0.5f) * 4.f;
        a1b1[b * 192 + t] = (t < CINC) ? (y + 1.f) : y;
    }
}

// ---------------- final: h*a1 + roll(h)*b1, shuffle(48), + x  (8 elems/thread) --
__global__ __launch_bounds__(256) void k_final(const _Float16* __restrict__ h,
                                               const float* __restrict__ xin,
                                               const float* __restrict__ a1b1,
                                               float* __restrict__ out)
{
    int q = blockIdx.x * 256 + threadIdx.x;      // 2,408,448 total (exact)
    int pos8 = q % 1568;                          // 12544/8
    int bo = q / 1568;
    int o = bo % CINC, b = bo / CINC;
    int c = (o % 48) * 2 + (o / 48);             // shuffle(48) folded
    int cn = (c + 1) % CINC;                      // channel roll

    float av = a1b1[b * 192 + c];
    float bv = a1b1[b * 192 + 96 + c];

    long hb = (long)b * CINC * HW;
    f16x8 hv8 = *(const f16x8*)(h + hb + (long)c  * HW + pos8 * 8);
    f16x8 h28 = *(const f16x8*)(h + hb + (long)cn * HW + pos8 * 8);

    long xo = ((long)(b * CINC + o)) * HW + pos8 * 8;
    f32x4 xv0 = *(const f32x4*)(xin + xo);
    f32x4 xv1 = *(const f32x4*)(xin + xo + 4);
    f32x4 r0, r1;
    #pragma unroll
    for (int j = 0; j < 4; ++j) {
        r0[j] = fmaf((float)hv8[j],     av, fmaf((float)h28[j],     bv, xv0[j]));
        r1[j] = fmaf((float)hv8[j + 4], av, fmaf((float)h28[j + 4], bv, xv1[j]));
    }
    *(f32x4*)(out + xo)     = r0;
    *(f32x4*)(out + xo + 4) = r1;
}

extern "C" void kernel_launch(void* const* d_in, const int* in_sizes, int n_in,
                              void* d_out, int out_size, void* d_ws, size_t ws_size,
                              hipStream_t stream)
{
    const float* x    = (const float*)d_in[0];
    const float* wdw1 = (const float*)d_in[1];
    const float* g1   = (const float*)d_in[2];
    const float* b1   = (const float*)d_in[3];
    const float* m1   = (const float*)d_in[4];
    const float* v1   = (const float*)d_in[5];
    const float* wdw2 = (const float*)d_in[6];
    const float* g2   = (const float*)d_in[7];
    const float* b2   = (const float*)d_in[8];
    const float* m2   = (const float*)d_in[9];
    const float* v2   = (const float*)d_in[10];
    const float* wpw  = (const float*)d_in[11];
    const float* g3   = (const float*)d_in[12];
    const float* b3   = (const float*)d_in[13];
    const float* m3   = (const float*)d_in[14];
    const float* v3   = (const float*)d_in[15];
    const float* fc1w = (const float*)d_in[16];
    const float* fc1b = (const float*)d_in[17];
    const float* fc2w = (const float*)d_in[18];
    const float* fc2b = (const float*)d_in[19];

    float* ws   = (float*)d_ws;
    float* sums = ws + WS_S;
    float* a1b1 = ws + WS_A1B1;
    _Float16* hbuf = (_Float16*)((char*)d_ws + WS_H_BYTES);
    float* out  = (float*)d_out;

    hipMemsetAsync(sums, 0, 1536 * sizeof(float), stream);
    k_prep<<<dim3(40), dim3(256), 0, stream>>>(
        wdw1, g1, b1, m1, v1, wdw2, g2, b2, m2, v2,
        wpw, g3, b3, m3, v3, ws);
    k_main12<<<dim3(896), dim3(256), 0, stream>>>(x, ws, sums, hbuf);
    k_gates<<<dim3(BATCH), dim3(192), 0, stream>>>(sums, fc1w, fc1b, fc2w, fc2b, a1b1);
    k_final<<<dim3(2408448 / 256), dim3(256), 0, stream>>>(hbuf, x, a1b1, out);
}

// Round 21
// 118.316 us; speedup vs baseline: 1.4903x; 1.4903x over previous
//
#include <hip/hip_runtime.h>
#include <hip/hip_bf16.h>

#define BATCH 16
#define CINC 96
#define HGT 112
#define WID 112
#define HW 12544          // 112*112
#define C1N 192
#define C2N 384
#define EPSV 1e-5f

typedef _Float16 f16x8 __attribute__((ext_vector_type(8)));
typedef _Float16 f16x4 __attribute__((ext_vector_type(4)));
typedef float    f32x4 __attribute__((ext_vector_type(4)));

// d_ws layout (float offsets unless noted)
#define WS_S      0        // 16*96 f32 h-sums (zeroed each launch)
#define WS_A1B1   1536     // 16*192 f32
#define WS_W1F    4608     // 192*3
#define WS_B1F    5184     // 192
#define WS_W2F    5376     // 384*3
#define WS_B2F    6528     // 384
#define WS_S3     6912     // 96
#define WS_B3     7008     // 96
#define WS_WPF_BYTES (7104*4)                    // f16 wpf[chunk][ks][rt][lane][8]
#define WS_H_BYTES   (WS_WPF_BYTES + CINC*C2N*2) // f16 h[16][96][12544] = 38.5 MB

// ---------------- prep: fold BN into weights; Wp -> chunk-contiguous fragments --
// wpf[(((ksg)*6+rt)*64+lane)*8+e] = Wp[rt*16+(lane&15)][ksg*32+(lane>>4)*8+e]
// Wp[m][k] = w_pw[m][(k%64)*6 + k/64]  (channel shuffle groups=6 folded)
__global__ void k_prep(const float* __restrict__ wdw1, const float* __restrict__ g1,
                       const float* __restrict__ bb1, const float* __restrict__ m1,
                       const float* __restrict__ v1,
                       const float* __restrict__ wdw2, const float* __restrict__ g2,
                       const float* __restrict__ bb2, const float* __restrict__ m2,
                       const float* __restrict__ v2,
                       const float* __restrict__ wpw, const float* __restrict__ g3,
                       const float* __restrict__ bb3, const float* __restrict__ m3,
                       const float* __restrict__ v3,
                       float* ws)
{
    int t = blockIdx.x * blockDim.x + threadIdx.x;
    int stride = gridDim.x * blockDim.x;
    float* w1f = ws + WS_W1F; float* b1f = ws + WS_B1F;
    float* w2f = ws + WS_W2F; float* b2f = ws + WS_B2F;
    float* s3  = ws + WS_S3;  float* b3f = ws + WS_B3;
    _Float16* wpf = (_Float16*)((char*)ws + WS_WPF_BYTES);

    for (int c = t; c < C1N; c += stride) {
        float s = g1[c] / sqrtf(v1[c] + EPSV);
        w1f[c*3+0] = wdw1[c*3+0] * s;
        w1f[c*3+1] = wdw1[c*3+1] * s;
        w1f[c*3+2] = wdw1[c*3+2] * s;
        b1f[c] = bb1[c] - m1[c] * s;
    }
    for (int c = t; c < C2N; c += stride) {
        float s = g2[c] / sqrtf(v2[c] + EPSV);
        w2f[c*3+0] = wdw2[c*3+0] * s;
        w2f[c*3+1] = wdw2[c*3+1] * s;
        w2f[c*3+2] = wdw2[c*3+2] * s;
        b2f[c] = bb2[c] - m2[c] * s;
    }
    for (int c = t; c < CINC; c += stride) {
        float s = g3[c] / sqrtf(v3[c] + EPSV);
        s3[c] = s; b3f[c] = bb3[c] - m3[c] * s;
    }
    for (int idx = t; idx < CINC * C2N; idx += stride) {
        int e = idx & 7;
        int l2 = idx >> 3;
        int lane = l2 & 63;
        int l3 = l2 >> 6;
        int rt = l3 % 6, ksg = l3 / 6;
        int m = rt * 16 + (lane & 15);
        int k = ksg * 32 + (lane >> 4) * 8 + e;
        int o = (k & 63) * 6 + (k >> 6);
        wpf[idx] = (_Float16)wpw[m * C2N + o];
    }
}

// x-data for one channel pair
struct PairX {
    f32x4 T[2], M[2], B[2];
    float eT[2], eM[2], eB[2];
};

// ---------------- main: preload-pipelined dw -> LDS Wp MFMA -> h+sums ----------
// block = 4 rows x 64 cols; thread = (row r, 4-col c4); 72 KB LDS -> 2 blk/CU
__global__ __launch_bounds__(256, 2) void k_main8(const float* __restrict__ x,
                                                  const float* __restrict__ ws,
                                                  float* __restrict__ sums,
                                                  _Float16* __restrict__ h_out)
{
    __shared__ __align__(16) char u_raw[256 * 208];   // u tile (slot-rotated); h_s aliases
    __shared__ __align__(16) f16x8 wpf_s[1152];       // Wp chunk fragments (18432 B)
    __shared__ float ssum[CINC];

    int t   = threadIdx.x;
    int bid = blockIdx.x;
    int logical = (bid & 7) * 112 + (bid >> 3);       // XCD-chunked (896 = 8*112)
    int b   = logical / 56;
    int rem = logical - b * 56;
    int y0  = (rem >> 1) * 4;
    int x0  = (rem & 1) * 48;

    int wv = t >> 6, lane = t & 63;
    int r = lane >> 4, c4 = lane & 15;
    int gy = y0 + r;
    int gc = x0 + 4 * c4;
    int col16 = c4, g = r;                            // MFMA-phase aliases

    const float* w1f = ws + WS_W1F; const float* b1f = ws + WS_B1F;
    const float* w2f = ws + WS_W2F; const float* b2f = ws + WS_B2F;

    if (t < CINC) ssum[t] = 0.f;

    bool ymok = gy >= 1;
    bool ypok = gy + 1 < HGT;
    bool isE  = (c4 == 0) | (c4 == 15);
    int  ecol = (c4 == 0) ? (x0 - 1) : (x0 + 64);
    bool ev   = isE && ((unsigned)ecol < (unsigned)WID);
    int  secol = ev ? ecol : 0;
    int  tm = ymok ? -WID : 0;
    int  tp = ypok ?  WID : 0;

    f32x4 acc[6][4];
    #pragma unroll
    for (int rt = 0; rt < 6; ++rt)
        #pragma unroll
        for (int ct = 0; ct < 4; ++ct) acc[rt][ct] = (f32x4){0.f, 0.f, 0.f, 0.f};

    const f16x8* wpf_g = (const f16x8*)((const char*)ws + WS_WPF_BYTES);
    long xb = (long)b * CINC * HW;
    const float* xw = x + xb + (long)gy * WID;        // + cu*HW + col

    int rotbase = 3 * r + c4;
    char* ub0 = u_raw + (r * 64 + 4 * c4) * 208;

    // prefetch chunk 0's Wp fragments into registers
    f16x8 nw0 = wpf_g[t];
    f16x8 nw1 = wpf_g[256 + t];
    f16x8 nw2 = wpf_g[512 + t];
    f16x8 nw3 = wpf_g[768 + t];
    f16x8 nw4 = nw0;
    if (t < 128) nw4 = wpf_g[1024 + t];

    #define LOADCH(dst, q, cuq) {                                         \
        const float* p_ = xw + (long)(cuq) * HW;                          \
        (dst).M[q] = *(const f32x4*)(p_ + gc);                            \
        (dst).T[q] = *(const f32x4*)(p_ + gc + tm);                       \
        (dst).B[q] = *(const f32x4*)(p_ + gc + tp);                       \
        if (isE) {                                                        \
            const float* e_ = p_ + secol;                                 \
            (dst).eM[q] = e_[0]; (dst).eT[q] = e_[tm]; (dst).eB[q] = e_[tp]; \
        } }

    for (int chunk = 0; chunk < 4; ++chunk) {
        if (chunk) __syncthreads();       // prev MFMA reads done before overwrite

        // stage Wp fragments from prefetch regs (pure ds_write, no global wait)
        wpf_s[t] = nw0;
        wpf_s[256 + t] = nw1;
        wpf_s[512 + t] = nw2;
        wpf_s[768 + t] = nw3;
        if (t < 128) wpf_s[1024 + t] = nw4;

        int cbase = chunk * 24 + wv * 6;
        PairX A, B;
        LOADCH(A, 0, cbase + 0)
        LOADCH(A, 1, cbase + 1)

        // 3 pairs, software-pipelined: load pair p+1 while computing pair p
        #pragma unroll
        for (int p = 0; p < 3; ++p) {
            if (p == 0) { LOADCH(B, 0, cbase + 2) LOADCH(B, 1, cbase + 3) }
            if (p == 1) { LOADCH(A, 0, cbase + 4) LOADCH(A, 1, cbase + 5) }
            PairX& C = (p == 1) ? B : A;

            f16x4 uv[2][4];
            #pragma unroll
            for (int q = 0; q < 2; ++q) {
                int cu = cbase + 2 * p + q;
                int c1a = cu * 2;
                float wa0 = w1f[c1a*3+0], wa1 = w1f[c1a*3+1], wa2 = w1f[c1a*3+2], ba = b1f[c1a];
                float wb0 = w1f[c1a*3+3], wb1 = w1f[c1a*3+4], wb2 = w1f[c1a*3+5], bb = b1f[c1a+1];

                float va[4], vb[4];
                #pragma unroll
                for (int j = 0; j < 4; ++j) {
                    float tt = ymok ? C.T[q][j] : 0.f;
                    float bt = ypok ? C.B[q][j] : 0.f;
                    va[j] = fmaf(wa0, tt, fmaf(wa1, C.M[q][j], fmaf(wa2, bt, ba)));
                    vb[j] = fmaf(wb0, tt, fmaf(wb1, C.M[q][j], fmaf(wb2, bt, bb)));
                }
                // conv2 zero-pads BN1 output: out-of-image edge column -> 0
                float etS = (ymok && ev) ? C.eT[q] : 0.f;
                float ebS = (ypok && ev) ? C.eB[q] : 0.f;
                float emS = ev ? C.eM[q] : 0.f;
                float vea = ev ? fmaf(wa0, etS, fmaf(wa1, emS, fmaf(wa2, ebS, ba))) : 0.f;
                float veb = ev ? fmaf(wb0, etS, fmaf(wb1, emS, fmaf(wb2, ebS, bb))) : 0.f;

                float vLa = __shfl(va[3], (lane + 63) & 63);
                float vLb = __shfl(vb[3], (lane + 63) & 63);
                float vRa = __shfl(va[0], (lane + 1) & 63);
                float vRb = __shfl(vb[0], (lane + 1) & 63);
                if (c4 == 0)  { vLa = vea; vLb = veb; }
                if (c4 == 15) { vRa = vea; vRb = veb; }

                int c2b = cu * 4;
                float pa[6] = {vLa, va[0], va[1], va[2], va[3], vRa};
                float pb[6] = {vLb, vb[0], vb[1], vb[2], vb[3], vRb};
                #pragma unroll
                for (int j = 0; j < 4; ++j) {
                    #pragma unroll
                    for (int jj = 0; jj < 4; ++jj) {
                        float p0 = (jj < 2) ? pa[j]     : pb[j];
                        float p1 = (jj < 2) ? pa[j + 1] : pb[j + 1];
                        float p2 = (jj < 2) ? pa[j + 2] : pb[j + 2];
                        float tv = fmaf(w2f[(c2b+jj)*3+0], p0,
                                   fmaf(w2f[(c2b+jj)*3+1], p1,
                                   fmaf(w2f[(c2b+jj)*3+2], p2, b2f[c2b+jj])));
                        uv[q][j][jj] = (_Float16)fminf(fmaxf(tv, 0.f), 6.f);
                    }
                }
            }
            // paired 16-B store: k-cell = wv*3+p, rotated
            int slot = (wv * 3 + p + rotbase) % 12;
            char* ubase = ub0 + slot * 16;
            #pragma unroll
            for (int j = 0; j < 4; ++j) {
                f16x8 w = __builtin_shufflevector(uv[0][j], uv[1][j], 0, 1, 2, 3, 4, 5, 6, 7);
                *(f16x8*)(ubase + j * 208) = w;
            }
        }

        // prefetch next chunk's Wp during barrier + MFMA
        if (chunk < 3) {
            int cb = (chunk + 1) * 1152;
            nw0 = wpf_g[cb + t];
            nw1 = wpf_g[cb + 256 + t];
            nw2 = wpf_g[cb + 512 + t];
            nw3 = wpf_g[cb + 768 + t];
            if (t < 128) nw4 = wpf_g[cb + 1024 + t];
        }
        __syncthreads();   // u + wpf_s ready

        // MFMA: acc += Wp[:, chunk slice] * u  (all operands in LDS)
        __builtin_amdgcn_s_setprio(1);
        #pragma unroll
        for (int ks = 0; ks < 3; ++ks) {
            f16x8 bfr[4];
            #pragma unroll
            for (int ct = 0; ct < 4; ++ct) {
                int pos = wv * 64 + ct * 16 + col16;
                int sl = (ks * 4 + g + 3 * wv + ((pos >> 2) & 15)) % 12;
                bfr[ct] = *(const f16x8*)(u_raw + pos * 208 + sl * 16);
            }
            #pragma unroll
            for (int rt = 0; rt < 6; ++rt) {
                f16x8 afr = wpf_s[(ks * 6 + rt) * 64 + lane];
                #pragma unroll
                for (int ct = 0; ct < 4; ++ct)
                    acc[rt][ct] = __builtin_amdgcn_mfma_f32_16x16x32_f16(afr, bfr[ct], acc[rt][ct], 0, 0, 0);
            }
        }
        __builtin_amdgcn_s_setprio(0);
    }
    __syncthreads();   // last MFMA reads done before aliasing u_raw with h

    // stage h (bn3, f16) into LDS: h_s[m][264]
    _Float16* h_s = (_Float16*)u_raw;
    const float* s3  = ws + WS_S3;
    const float* b3f = ws + WS_B3;
    #pragma unroll
    for (int rt = 0; rt < 6; ++rt) {
        #pragma unroll
        for (int ct = 0; ct < 4; ++ct) {
            int p = wv * 64 + ct * 16 + col16;
            #pragma unroll
            for (int rr = 0; rr < 4; ++rr) {
                int m = rt * 16 + g * 4 + rr;
                h_s[m * 264 + p] = (_Float16)fmaf(acc[rt][ct][rr], s3[m], b3f[m]);
            }
        }
    }
    __syncthreads();

    // coalesced full-line h stores + channel sums (overlap cols masked)
    #pragma unroll
    for (int i = 0; i < 12; ++i) {
        int flat = i * 2048 + t * 8;           // covers 96*256 exactly
        int m = flat >> 8;
        int p = flat & 255;
        f16x8 hv = *(const f16x8*)(h_s + m * 264 + p);
        int row = y0 + (p >> 6);
        int colg = x0 + (p & 63);
        *(f16x8*)(h_out + ((long)(b * CINC + m)) * HW + (long)row * WID + colg) = hv;

        float s = 0.f;
        if (!(x0 == 48 && (p & 63) < 16)) {    // overlap cols 48..63 counted by half-0
            #pragma unroll
            for (int e = 0; e < 8; ++e) s += (float)hv[e];
        }
        s += __shfl_xor(s, 1);
        s += __shfl_xor(s, 2);
        s += __shfl_xor(s, 4);
        s += __shfl_xor(s, 8);
        s += __shfl_xor(s, 16);
        if ((lane & 31) == 0) atomicAdd(&ssum[m], s);
    }
    __syncthreads();
    if (t < CINC) atomicAdd(&sums[b * CINC + t], ssum[t]);
}

// ---------------- gates: mean(h) -> fc1+relu -> fc2 -> hardsig -> a1,b1 -------
__global__ __launch_bounds__(192) void k_gates(const float* __restrict__ sums,
                                               const float* __restrict__ fc1w,
                                               const float* __restrict__ fc1b,
                                               const float* __restrict__ fc2w,
                                               const float* __restrict__ fc2b,
                                               float* __restrict__ a1b1)
{
    __shared__ float mean_s[CINC];
    __shared__ float mid[24];
    int b = blockIdx.x;
    int t = threadIdx.x;     // 192

    if (t < CINC) mean_s[t] = sums[b * CINC + t] * (1.0f / 12544.0f);
    __syncthreads();
    if (t < 24) {
        float d = fc1b[t];
        #pragma unroll 4
        for (int c = 0; c < CINC; ++c) d = fmaf(fc1w[t * CINC + c], mean_s[c], d);
        mid[t] = fmaxf(d, 0.f);
    }
    __syncthreads();
    {
        float d = fc2b[t];
        #pragma unroll
        for (int j = 0; j < 24; ++j) d = fmaf(fc2w[t * 24 + j], mid[j], d);
        float y = fminf(fmaxf(d + 3.f, 0.f), 6.f) * (1.f / 6.f);
        y = (y - 0.5f) * 4.f;
        a1b1[b * 192 + t] = (t < CINC) ? (y + 1.f) : y;
    }
}

// ---------------- final: h*a1 + roll(h)*b1, shuffle(48), + x (pure streaming) --
__global__ __launch_bounds__(256) void k_final(const _Float16* __restrict__ h,
                                               const float* __restrict__ xin,
                                               const float* __restrict__ a1b1,
                                               float* __restrict__ out)
{
    int q = blockIdx.x * 256 + threadIdx.x;      // 4,816,896 quads total (exact)
    int pos4 = q % 3136;
    int bo = q / 3136;
    int o = bo % CINC, b = bo / CINC;
    int c = (o % 48) * 2 + (o / 48);             // shuffle(48) folded
    int cn = (c + 1) % CINC;                      // channel roll

    float av = a1b1[b * 192 + c];
    float bv = a1b1[b * 192 + 96 + c];

    long hb = (long)b * CINC * HW;
    f16x4 hv4 = *(const f16x4*)(h + hb + (long)c  * HW + pos4 * 4);
    f16x4 h2v = *(const f16x4*)(h + hb + (long)cn * HW + pos4 * 4);

    long xo = ((long)(b * CINC + o)) * HW + pos4 * 4;
    f32x4 xv = *(const f32x4*)(xin + xo);
    f32x4 rr;
    #pragma unroll
    for (int j = 0; j < 4; ++j)
        rr[j] = fmaf((float)hv4[j], av, fmaf((float)h2v[j], bv, xv[j]));
    *(f32x4*)(out + xo) = rr;
}

extern "C" void kernel_launch(void* const* d_in, const int* in_sizes, int n_in,
                              void* d_out, int out_size, void* d_ws, size_t ws_size,
                              hipStream_t stream)
{
    const float* x    = (const float*)d_in[0];
    const float* wdw1 = (const float*)d_in[1];
    const float* g1   = (const float*)d_in[2];
    const float* b1   = (const float*)d_in[3];
    const float* m1   = (const float*)d_in[4];
    const float* v1   = (const float*)d_in[5];
    const float* wdw2 = (const float*)d_in[6];
    const float* g2   = (const float*)d_in[7];
    const float* b2   = (const float*)d_in[8];
    const float* m2   = (const float*)d_in[9];
    const float* v2   = (const float*)d_in[10];
    const float* wpw  = (const float*)d_in[11];
    const float* g3   = (const float*)d_in[12];
    const float* b3   = (const float*)d_in[13];
    const float* m3   = (const float*)d_in[14];
    const float* v3   = (const float*)d_in[15];
    const float* fc1w = (const float*)d_in[16];
    const float* fc1b = (const float*)d_in[17];
    const float* fc2w = (const float*)d_in[18];
    const float* fc2b = (const float*)d_in[19];

    float* ws   = (float*)d_ws;
    float* sums = ws + WS_S;
    float* a1b1 = ws + WS_A1B1;
    _Float16* hbuf = (_Float16*)((char*)d_ws + WS_H_BYTES);
    float* out  = (float*)d_out;

    hipMemsetAsync(sums, 0, 1536 * sizeof(float), stream);
    k_prep<<<dim3(40), dim3(256), 0, stream>>>(
        wdw1, g1, b1, m1, v1, wdw2, g2, b2, m2, v2,
        wpw, g3, b3, m3, v3, ws);
    k_main8<<<dim3(896), dim3(256), 0, stream>>>(x, ws, sums, hbuf);
    k_gates<<<dim3(BATCH), dim3(192), 0, stream>>>(sums, fc1w, fc1b, fc2w, fc2b, a1b1);
    k_final<<<dim3(4816896 / 256), dim3(256), 0, stream>>>(hbuf, x, a1b1, out);
}